// Round 15
// baseline (60.646 us; speedup 1.0000x reference)
//
#include <hip/hip_runtime.h>
#include <cstdint>
#include <cstddef>

#define NUM_CLASSES 80
#define NCLS1 81
#define NCAND 200
#define MAX_SEGS 50
#define FH 128
#define FW 128
#define NMS_THR 0.65f
#define CLS_OFFSET 129.0f
#define OH 512
#define OW 512

typedef unsigned int u32;
typedef unsigned long long u64;
typedef float v4f __attribute__((ext_vector_type(4)));

__device__ __forceinline__ u32 ord_of_float(float f) {
  u32 u = __float_as_uint(f);
  return (u & 0x80000000u) ? ~u : (u | 0x80000000u);
}
__device__ __forceinline__ float float_of_ord(u32 o) {
  u32 u = (o & 0x80000000u) ? (o ^ 0x80000000u) : ~o;
  return __uint_as_float(u);
}

// ---- K1: per-feature box + fused key build ---------------------------------
__global__ void __launch_bounds__(256)
boxkey_kernel(const float* __restrict__ cls, const float* __restrict__ seg,
              int F, float* __restrict__ boxes, u64* __restrict__ keysWs) {
  int g = blockIdx.x;
  int t = threadIdx.x;
  __shared__ u32 rowBits[4];
  __shared__ u32 colBits[4];
  __shared__ int sValid;
  if (t < 4) { rowBits[t] = 0; colBits[t] = 0; }
  __syncthreads();

  const v4f* base = reinterpret_cast<const v4f*>(seg + (size_t)g * (FH * FW));
  int c4 = t & 31;
  int rbase = t >> 5;
  int lane = t & 63;
  bool cb0 = false, cb1 = false, cb2 = false, cb3 = false;
  u32 rb[4] = {0, 0, 0, 0};
#pragma unroll
  for (int it = 0; it < 16; ++it) {
    int r = rbase + (it << 3);
    v4f v = base[r * 32 + c4];
    bool p0 = v.x > 0.0f, p1 = v.y > 0.0f, p2 = v.z > 0.0f, p3 = v.w > 0.0f;
    cb0 |= p0; cb1 |= p1; cb2 |= p2; cb3 |= p3;
    u64 b = __ballot(p0 | p1 | p2 | p3);
    if (lane == 0) {
      if ((u32)b) rb[r >> 5] |= 1u << (r & 31);
      int r2 = r + 1;
      if ((u32)(b >> 32)) rb[r2 >> 5] |= 1u << (r2 & 31);
    }
  }
  if (lane == 0) {
#pragma unroll
    for (int w = 0; w < 4; ++w)
      if (rb[w]) atomicOr(&rowBits[w], rb[w]);
  }
  u32 nib = (u32)cb0 | ((u32)cb1 << 1) | ((u32)cb2 << 2) | ((u32)cb3 << 3);
  if (nib) atomicOr(&colBits[c4 >> 3], nib << ((c4 & 7) * 4));
  __syncthreads();

  if (t == 0) {
    int firstR = -1, lastR = -1;
    for (int w = 0; w < 4; ++w) {
      u32 b = rowBits[w];
      if (b) { if (firstR < 0) firstR = w * 32 + (__ffs(b) - 1); lastR = w * 32 + 31 - __clz((int)b); }
    }
    int firstC = -1, lastC = -1;
    for (int w = 0; w < 4; ++w) {
      u32 b = colBits[w];
      if (b) { if (firstC < 0) firstC = w * 32 + (__ffs(b) - 1); lastC = w * 32 + 31 - __clz((int)b); }
    }
    float x1, y1, x2, y2; int valid;
    if (firstR < 0) {
      valid = 0; x1 = 0.0f; y1 = 0.0f; x2 = (float)FW; y2 = (float)FH;
    } else {
      valid = 1;
      y1 = (float)firstR; y2 = (float)(lastR + 1);
      x1 = (float)firstC; x2 = (float)(lastC + 1);
    }
    boxes[g * 4 + 0] = x1; boxes[g * 4 + 1] = y1;
    boxes[g * 4 + 2] = x2; boxes[g * 4 + 3] = y2;
    sValid = valid;
  }
  __syncthreads();

  if (t < NUM_CLASSES) {
    int img = g / F;
    int f_local = g - img * F;
    float logit = cls[(size_t)g * NCLS1 + t];
    float s = sValid ? (1.0f / (1.0f + expf(-logit))) : -1.0f;
    int idx = f_local * NUM_CLASSES + t;
    u64 key = ((u64)ord_of_float(s) << 13) | (u64)(8191 - idx);  // distinct, nonzero
    keysWs[(size_t)img * (F * NUM_CLASSES) + idx] = key;
  }
}

// ---- K2: exact top-200 + IoU + PARALLEL Jacobi-fixpoint greedy NMS ---------
__global__ void __launch_bounds__(1024)
select_kernel(const u64* __restrict__ keysWs, const float* __restrict__ boxes,
              int F, float* __restrict__ out,
              int* __restrict__ finFeatWs, int* __restrict__ finValidWs,
              size_t scoresOff, size_t validOff) {
  const int img = blockIdx.x;
  const int tid = threadIdx.x;
  const int NS = F * NUM_CLASSES;  // 8000

  __shared__ u32 hist[2048];
  __shared__ u64 gk[1024];
  __shared__ int cntG;
  __shared__ u64 sPrefix;
  __shared__ int sR, sDone;
  __shared__ float candScore[NCAND];
  __shared__ int candFeat[NCAND], candLabel[NCAND];
  __shared__ float candBox[NCAND][4];
  __shared__ u64 supp[NCAND][4];
  __shared__ u64 keepW[4];
  __shared__ int sChanged;
  __shared__ int finIdx[MAX_SEGS];
  __shared__ int finCnt;

  // (a) load prebuilt keys: 8/thread, coalesced, L2-hot
  const u64* kbase = keysWs + (size_t)img * NS;
  u64 rkey[8];
#pragma unroll
  for (int p = 0; p < 8; ++p) {
    int idx = tid + (p << 10);
    rkey[p] = (idx < NS) ? kbase[idx] : 0;
  }
  if (tid == 0) { sPrefix = 0; sR = NCAND; sDone = 0; cntG = 0; }

  // (b) 2048-way radix descent over 45-bit keys
  const int shifts[4] = {34, 23, 12, 1};
  int fsh = 1;
  for (int lev = 0; lev < 4; ++lev) {
    int shift = shifts[lev];
    for (int i = tid; i < 2048; i += 1024) hist[i] = 0;
    __syncthreads();
    u64 pf = sPrefix;
    int R = sR;
#pragma unroll
    for (int p = 0; p < 8; ++p) {
      int idx = tid + (p << 10);
      u64 k = rkey[p];
      if (idx < NS && (k >> (shift + 11)) == pf)
        atomicAdd(&hist[(k >> shift) & 2047], 1u);
    }
    __syncthreads();
    if (tid < 64) {
      int lane = tid;
      u32 lsum = 0;
      for (int b = 0; b < 32; ++b) lsum += hist[lane * 32 + b];
      u32 suf = lsum;
#pragma unroll
      for (int d = 1; d < 64; d <<= 1) {
        u32 o = __shfl_down(suf, d);
        if (lane + d < 64) suf += o;
      }
      u32 above = suf - lsum;               // bins >= (lane+1)*32
      if (above < (u32)R && suf >= (u32)R) {
        u32 cum = above; int vb = 0; u32 hv = 0;
        for (int b = 31; b >= 0; --b) {
          u32 hb = hist[lane * 32 + b];
          if (cum + hb >= (u32)R) { vb = lane * 32 + b; hv = hb; break; }
          cum += hb;
        }
        int newR = R - (int)cum;
        sPrefix = (pf << 11) | (u64)vb;
        sR = newR;
        if ((NCAND - newR) + (int)hv <= 1024) sDone = 1;
      }
    }
    __syncthreads();
    if (sDone) { fsh = shift; break; }
  }
  u64 fpfx = sPrefix;

  // (c) gather all keys with (key>>fsh) >= fpfx  (200 <= count <= 1024)
#pragma unroll
  for (int p = 0; p < 8; ++p) {
    int idx = tid + (p << 10);
    u64 k = rkey[p];
    if (idx < NS && (k >> fsh) >= fpfx) {
      int pos = atomicAdd(&cntG, 1);
      if (pos < 1024) gk[pos] = k;
    }
  }
  for (int i = tid; i < NCAND * 4; i += 1024) supp[i >> 2][i & 3] = 0;
  __syncthreads();
  int n = cntG < 1024 ? cntG : 1024;

  // (d) exact rank among gathered (distinct keys -> dense unique ranks)
  if (tid < n) {
    u64 k = gk[tid];
    int rank = 0;
    for (int s = 0; s < n; ++s) rank += (gk[s] > k) ? 1 : 0;
    if (rank < NCAND) {
      int idx = 8191 - (int)(k & 0x1FFF);
      u32 o = (u32)(k >> 13);
      int f = idx / NUM_CLASSES, c = idx - f * NUM_CLASSES;
      float sc = float_of_ord(o);
      float off = (float)c * CLS_OFFSET;
      int gg = img * F + f;
      candScore[rank] = sc; candFeat[rank] = f; candLabel[rank] = c;
      candBox[rank][0] = boxes[gg * 4 + 0] + off;
      candBox[rank][1] = boxes[gg * 4 + 1] + off;
      candBox[rank][2] = boxes[gg * 4 + 2] + off;
      candBox[rank][3] = boxes[gg * 4 + 3] + off;
    }
  }
  __syncthreads();

  // (e) pairwise IoU, folded triangular indexing: 19900 pairs (j < i)
  for (int p = tid; p < (NCAND * (NCAND - 1)) / 2; p += 1024) {
    int r = p / (NCAND / 2), cc = p - r * (NCAND / 2);
    int i, j;
    if (cc <= r) { i = r + 1; j = cc; }
    else         { i = NCAND - 1 - r; j = NCAND - 1 - cc; }
    float ax1 = candBox[i][0], ay1 = candBox[i][1], ax2 = candBox[i][2], ay2 = candBox[i][3];
    float bx1 = candBox[j][0], by1 = candBox[j][1], bx2 = candBox[j][2], by2 = candBox[j][3];
    float areaA = (ax2 - ax1) * (ay2 - ay1);
    float areaB = (bx2 - bx1) * (by2 - by1);
    float lx = fmaxf(ax1, bx1), ly = fmaxf(ay1, by1);
    float rx = fminf(ax2, bx2), ry = fminf(ay2, by2);
    float w = fmaxf(rx - lx, 0.0f), h = fmaxf(ry - ly, 0.0f);
    float inter = w * h;
    float iou = inter / ((areaA + areaB - inter) + 1e-9f);
    if (iou > NMS_THR) atomicOr(&supp[i][j >> 6], 1ull << (j & 63));
  }
  __syncthreads();

  // (f) PARALLEL greedy NMS via Jacobi fixpoint (converges to serial-greedy)
  bool valid_i = (tid < NCAND) ? (candScore[tid] > -0.5f) : false;
  {
    u64 b = __ballot(valid_i);
    if ((tid & 63) == 0 && (tid >> 6) < 4) keepW[tid >> 6] = b;
  }
  __syncthreads();
  for (int it = 0; it < NCAND; ++it) {
    if (tid == 0) sChanged = 0;
    __syncthreads();
    bool newk = false;
    if (tid < NCAND) {
      bool sup = ((supp[tid][0] & keepW[0]) | (supp[tid][1] & keepW[1]) |
                  (supp[tid][2] & keepW[2]) | (supp[tid][3] & keepW[3])) != 0ull;
      newk = valid_i && !sup;
    }
    u64 b = __ballot(newk);
    __syncthreads();                 // everyone done reading old keepW
    if ((tid & 63) == 0 && (tid >> 6) < 4) {
      if (b != keepW[tid >> 6]) { keepW[tid >> 6] = b; atomicOr(&sChanged, 1); }
    }
    __syncthreads();
    if (!sChanged) break;
  }

  // (g) parallel top-50 gather: kept in keep-order, then non-kept ascending
  {
    int keptN = __popcll(keepW[0]) + __popcll(keepW[1]) +
                __popcll(keepW[2]) + __popcll(keepW[3]);
    if (tid == 0) finCnt = keptN < MAX_SEGS ? keptN : MAX_SEGS;
    if (tid < NCAND) {
      int w = tid >> 6, b = tid & 63;
      u64 below = (b == 0) ? 0ull : (keepW[w] & (~0ull >> (64 - b)));
      int rank = __popcll(below);
      for (int ww = 0; ww < w; ++ww) rank += __popcll(keepW[ww]);
      bool kept = (keepW[w] >> b) & 1ull;
      if (kept) {
        if (rank < MAX_SEGS) finIdx[rank] = tid;
      } else if (keptN < MAX_SEGS) {
        int pos = keptN + (tid - rank);   // tid - rank = #non-kept below tid
        if (pos < MAX_SEGS) finIdx[pos] = tid;
      }
    }
  }
  __syncthreads();

  if (tid < MAX_SEGS) {
    int keptN = finCnt;
    int i = finIdx[tid];
    bool v = tid < keptN;
    int o = img * MAX_SEGS + tid;
    out[o] = (float)candLabel[i];
    out[scoresOff + (size_t)o] = v ? candScore[i] : 0.0f;
    out[validOff + (size_t)o] = v ? 1.0f : 0.0f;
    finFeatWs[o] = candFeat[i];
    finValidWs[o] = v ? 1 : 0;
  }
}

// ---------------- K3: bilinear 128->512 upsample + threshold ----------------
// NT stores: mask output is write-once/never-read; avoid L2 write-allocate.
__global__ void __launch_bounds__(256)
interp_kernel(const float* __restrict__ seg, const int* __restrict__ finFeat,
              const int* __restrict__ finValid, float* __restrict__ outMasks, int F) {
  int bm = blockIdx.x;          // img*MAX_SEGS + m
  int g8 = blockIdx.y;          // src quads 8g8..8g8+7 -> out rows 32g8..32g8+31
  int tid = threadIdx.x;
  int q = tid & 127;            // col group -> cols 4q..4q+3
  int sub = tid >> 7;           // 0..1

  float* omask = outMasks + (size_t)bm * (OH * OW);

  if (!finValid[bm]) {
    v4f z = {0.0f, 0.0f, 0.0f, 0.0f};
#pragma unroll
    for (int k = 0; k < 4; ++k) {
      int Q = 8 * g8 + sub + 2 * k;
      float* ob = omask + (size_t)(4 * Q) * OW;
#pragma unroll
      for (int r = 0; r < 4; ++r)
        __builtin_nontemporal_store(z, reinterpret_cast<v4f*>(ob + r * OW) + q);
    }
    return;
  }
  int img = bm / MAX_SEGS;
  int f = finFeat[bm];
  const float* src = seg + ((size_t)(img * F + f)) * (FH * FW);

  __shared__ float lds[10][FW];
  {
    const v4f* s4 = reinterpret_cast<const v4f*>(src);
    for (int i = tid; i < 10 * 32; i += 256) {
      int lr = i >> 5;
      int c4 = i & 31;
      int srow = 8 * g8 - 1 + lr;
      srow = srow < 0 ? 0 : (srow > FH - 1 ? FH - 1 : srow);
      *reinterpret_cast<v4f*>(&lds[lr][c4 * 4]) = s4[srow * 32 + c4];
    }
  }
  __syncthreads();

  int qm = (q > 0) ? q - 1 : 0;
  int qp = (q < FW - 1) ? q + 1 : FW - 1;

#pragma unroll
  for (int k = 0; k < 4; ++k) {
    int Q = 8 * g8 + sub + 2 * k;
    int lr = Q - 8 * g8;
    const float* prm = lds[lr];
    const float* pr0 = lds[lr + 1];
    const float* prp = lds[lr + 2];
    float* obase = omask + (size_t)(4 * Q) * OW;

    double am = prm[qm], a0 = pr0[qm], ap = prp[qm];
    double bmv = prm[q], b0 = pr0[q], bp = prp[q];
    double cm = prm[qp], c0 = pr0[qp], cp = prp[qp];

    double A[4], Bv[4], C[4];
    if (Q == 0) {
      A[0] = a0; Bv[0] = b0; C[0] = c0;
      A[1] = a0; Bv[1] = b0; C[1] = c0;
    } else {
      A[0] = 0.375 * am + 0.625 * a0;  Bv[0] = 0.375 * bmv + 0.625 * b0;  C[0] = 0.375 * cm + 0.625 * c0;
      A[1] = 0.125 * am + 0.875 * a0;  Bv[1] = 0.125 * bmv + 0.875 * b0;  C[1] = 0.125 * cm + 0.875 * c0;
    }
    if (Q == 127) {
      A[2] = a0; Bv[2] = b0; C[2] = c0;
      A[3] = a0; Bv[3] = b0; C[3] = c0;
    } else {
      A[2] = 0.875 * a0 + 0.125 * ap;  Bv[2] = 0.875 * b0 + 0.125 * bp;  C[2] = 0.875 * c0 + 0.125 * cp;
      A[3] = 0.625 * a0 + 0.375 * ap;  Bv[3] = 0.625 * b0 + 0.375 * bp;  C[3] = 0.625 * c0 + 0.375 * cp;
    }

#pragma unroll
    for (int r = 0; r < 4; ++r) {
      double px0 = (q == 0)      ? Bv[r] : (0.375 * A[r] + 0.625 * Bv[r]);
      double px1 = (q == 0)      ? Bv[r] : (0.125 * A[r] + 0.875 * Bv[r]);
      double px2 = (q == FW - 1) ? Bv[r] : (0.875 * Bv[r] + 0.125 * C[r]);
      double px3 = (q == FW - 1) ? Bv[r] : (0.625 * Bv[r] + 0.375 * C[r]);
      v4f res;
      res.x = (px0 > 0.0) ? 1.0f : 0.0f;
      res.y = (px1 > 0.0) ? 1.0f : 0.0f;
      res.z = (px2 > 0.0) ? 1.0f : 0.0f;
      res.w = (px3 > 0.0) ? 1.0f : 0.0f;
      __builtin_nontemporal_store(res, reinterpret_cast<v4f*>(obase + r * OW) + q);
    }
  }
}

// ---------------- host launch ----------------
extern "C" void kernel_launch(void* const* d_in, const int* in_sizes, int n_in,
                              void* d_out, int out_size, void* d_ws, size_t ws_size,
                              hipStream_t stream) {
  const float* cls = (const float*)d_in[0];
  const float* seg = (const float*)d_in[1];
  const int B = 2;  // fixed by setup_inputs
  int totalF = in_sizes[0] / NCLS1;      // 200
  int F = totalF / B;                    // 100

  float* out = (float*)d_out;
  u64*   keysWs  = (u64*)d_ws;                              // B*8000 u64
  float* boxes   = (float*)(keysWs + (size_t)B * F * NUM_CLASSES);
  int*   finFeat = (int*)(boxes + (size_t)totalF * 4);
  int*   finValid = finFeat + B * MAX_SEGS;

  const size_t labelsN   = (size_t)B * MAX_SEGS;             // 100
  const size_t maskElems = (size_t)B * MAX_SEGS * OH * OW;   // 26,214,400
  const size_t scoresOff = labelsN + maskElems;
  const size_t validOff  = scoresOff + labelsN;

  boxkey_kernel<<<totalF, 256, 0, stream>>>(cls, seg, F, boxes, keysWs);
  select_kernel<<<B, 1024, 0, stream>>>(keysWs, boxes, F, out,
                                        finFeat, finValid, scoresOff, validOff);
  interp_kernel<<<dim3(B * MAX_SEGS, 16), 256, 0, stream>>>(seg, finFeat, finValid,
                                                            out + labelsN, F);
}

// Round 16
// 49.883 us; speedup vs baseline: 1.2158x; 1.2158x over previous
//
#include <hip/hip_runtime.h>
#include <cstdint>
#include <cstddef>

#define NUM_CLASSES 80
#define NCLS1 81
#define NCAND 200
#define MAX_SEGS 50
#define FH 128
#define FW 128
#define NMS_THR 0.65f
#define CLS_OFFSET 129.0f
#define OH 512
#define OW 512

typedef unsigned int u32;
typedef unsigned long long u64;
typedef float v4f __attribute__((ext_vector_type(4)));

__device__ __forceinline__ u32 ord_of_float(float f) {
  u32 u = __float_as_uint(f);
  return (u & 0x80000000u) ? ~u : (u | 0x80000000u);
}
__device__ __forceinline__ float float_of_ord(u32 o) {
  u32 u = (o & 0x80000000u) ? (o ^ 0x80000000u) : ~o;
  return __uint_as_float(u);
}

// ---- K1: per-feature box + fused key build ---------------------------------
__global__ void __launch_bounds__(256)
boxkey_kernel(const float* __restrict__ cls, const float* __restrict__ seg,
              int F, float* __restrict__ boxes, u64* __restrict__ keysWs) {
  int g = blockIdx.x;
  int t = threadIdx.x;
  __shared__ u32 rowBits[4];
  __shared__ u32 colBits[4];
  __shared__ int sValid;
  if (t < 4) { rowBits[t] = 0; colBits[t] = 0; }
  __syncthreads();

  const v4f* base = reinterpret_cast<const v4f*>(seg + (size_t)g * (FH * FW));
  int c4 = t & 31;
  int rbase = t >> 5;
  int lane = t & 63;
  bool cb0 = false, cb1 = false, cb2 = false, cb3 = false;
  u32 rb[4] = {0, 0, 0, 0};
#pragma unroll
  for (int it = 0; it < 16; ++it) {
    int r = rbase + (it << 3);
    v4f v = base[r * 32 + c4];
    bool p0 = v.x > 0.0f, p1 = v.y > 0.0f, p2 = v.z > 0.0f, p3 = v.w > 0.0f;
    cb0 |= p0; cb1 |= p1; cb2 |= p2; cb3 |= p3;
    u64 b = __ballot(p0 | p1 | p2 | p3);
    if (lane == 0) {
      if ((u32)b) rb[r >> 5] |= 1u << (r & 31);
      int r2 = r + 1;
      if ((u32)(b >> 32)) rb[r2 >> 5] |= 1u << (r2 & 31);
    }
  }
  if (lane == 0) {
#pragma unroll
    for (int w = 0; w < 4; ++w)
      if (rb[w]) atomicOr(&rowBits[w], rb[w]);
  }
  u32 nib = (u32)cb0 | ((u32)cb1 << 1) | ((u32)cb2 << 2) | ((u32)cb3 << 3);
  if (nib) atomicOr(&colBits[c4 >> 3], nib << ((c4 & 7) * 4));
  __syncthreads();

  if (t == 0) {
    int firstR = -1, lastR = -1;
    for (int w = 0; w < 4; ++w) {
      u32 b = rowBits[w];
      if (b) { if (firstR < 0) firstR = w * 32 + (__ffs(b) - 1); lastR = w * 32 + 31 - __clz((int)b); }
    }
    int firstC = -1, lastC = -1;
    for (int w = 0; w < 4; ++w) {
      u32 b = colBits[w];
      if (b) { if (firstC < 0) firstC = w * 32 + (__ffs(b) - 1); lastC = w * 32 + 31 - __clz((int)b); }
    }
    float x1, y1, x2, y2; int valid;
    if (firstR < 0) {
      valid = 0; x1 = 0.0f; y1 = 0.0f; x2 = (float)FW; y2 = (float)FH;
    } else {
      valid = 1;
      y1 = (float)firstR; y2 = (float)(lastR + 1);
      x1 = (float)firstC; x2 = (float)(lastC + 1);
    }
    boxes[g * 4 + 0] = x1; boxes[g * 4 + 1] = y1;
    boxes[g * 4 + 2] = x2; boxes[g * 4 + 3] = y2;
    sValid = valid;
  }
  __syncthreads();

  if (t < NUM_CLASSES) {
    int img = g / F;
    int f_local = g - img * F;
    float logit = cls[(size_t)g * NCLS1 + t];
    float s = sValid ? (1.0f / (1.0f + expf(-logit))) : -1.0f;
    int idx = f_local * NUM_CLASSES + t;
    u64 key = ((u64)ord_of_float(s) << 13) | (u64)(8191 - idx);  // distinct, nonzero
    keysWs[(size_t)img * (F * NUM_CLASSES) + idx] = key;
  }
}

// ---- K2: exact top-200 + IoU + PARALLEL Jacobi-fixpoint greedy NMS ---------
__global__ void __launch_bounds__(1024)
select_kernel(const u64* __restrict__ keysWs, const float* __restrict__ boxes,
              int F, float* __restrict__ out,
              int* __restrict__ finFeatWs, int* __restrict__ finValidWs,
              size_t scoresOff, size_t validOff) {
  const int img = blockIdx.x;
  const int tid = threadIdx.x;
  const int NS = F * NUM_CLASSES;  // 8000

  __shared__ u32 hist[2048];
  __shared__ u64 gk[1024];
  __shared__ int cntG;
  __shared__ u64 sPrefix;
  __shared__ int sR, sDone;
  __shared__ float candScore[NCAND];
  __shared__ int candFeat[NCAND], candLabel[NCAND];
  __shared__ float candBox[NCAND][4];
  __shared__ u64 supp[NCAND][4];
  __shared__ u64 keepW[4];
  __shared__ int sChanged;
  __shared__ int finIdx[MAX_SEGS];
  __shared__ int finCnt;

  // (a) load prebuilt keys: 8/thread, coalesced, L2-hot
  const u64* kbase = keysWs + (size_t)img * NS;
  u64 rkey[8];
#pragma unroll
  for (int p = 0; p < 8; ++p) {
    int idx = tid + (p << 10);
    rkey[p] = (idx < NS) ? kbase[idx] : 0;
  }
  if (tid == 0) { sPrefix = 0; sR = NCAND; sDone = 0; cntG = 0; }

  // (b) 2048-way radix descent over 45-bit keys
  const int shifts[4] = {34, 23, 12, 1};
  int fsh = 1;
  for (int lev = 0; lev < 4; ++lev) {
    int shift = shifts[lev];
    for (int i = tid; i < 2048; i += 1024) hist[i] = 0;
    __syncthreads();
    u64 pf = sPrefix;
    int R = sR;
#pragma unroll
    for (int p = 0; p < 8; ++p) {
      int idx = tid + (p << 10);
      u64 k = rkey[p];
      if (idx < NS && (k >> (shift + 11)) == pf)
        atomicAdd(&hist[(k >> shift) & 2047], 1u);
    }
    __syncthreads();
    if (tid < 64) {
      int lane = tid;
      u32 lsum = 0;
      for (int b = 0; b < 32; ++b) lsum += hist[lane * 32 + b];
      u32 suf = lsum;
#pragma unroll
      for (int d = 1; d < 64; d <<= 1) {
        u32 o = __shfl_down(suf, d);
        if (lane + d < 64) suf += o;
      }
      u32 above = suf - lsum;               // bins >= (lane+1)*32
      if (above < (u32)R && suf >= (u32)R) {
        u32 cum = above; int vb = 0; u32 hv = 0;
        for (int b = 31; b >= 0; --b) {
          u32 hb = hist[lane * 32 + b];
          if (cum + hb >= (u32)R) { vb = lane * 32 + b; hv = hb; break; }
          cum += hb;
        }
        int newR = R - (int)cum;
        sPrefix = (pf << 11) | (u64)vb;
        sR = newR;
        if ((NCAND - newR) + (int)hv <= 1024) sDone = 1;
      }
    }
    __syncthreads();
    if (sDone) { fsh = shift; break; }
  }
  u64 fpfx = sPrefix;

  // (c) gather all keys with (key>>fsh) >= fpfx  (200 <= count <= 1024)
#pragma unroll
  for (int p = 0; p < 8; ++p) {
    int idx = tid + (p << 10);
    u64 k = rkey[p];
    if (idx < NS && (k >> fsh) >= fpfx) {
      int pos = atomicAdd(&cntG, 1);
      if (pos < 1024) gk[pos] = k;
    }
  }
  for (int i = tid; i < NCAND * 4; i += 1024) supp[i >> 2][i & 3] = 0;
  __syncthreads();
  int n = cntG < 1024 ? cntG : 1024;

  // (d) exact rank among gathered (distinct keys -> dense unique ranks)
  if (tid < n) {
    u64 k = gk[tid];
    int rank = 0;
    for (int s = 0; s < n; ++s) rank += (gk[s] > k) ? 1 : 0;
    if (rank < NCAND) {
      int idx = 8191 - (int)(k & 0x1FFF);
      u32 o = (u32)(k >> 13);
      int f = idx / NUM_CLASSES, c = idx - f * NUM_CLASSES;
      float sc = float_of_ord(o);
      float off = (float)c * CLS_OFFSET;
      int gg = img * F + f;
      candScore[rank] = sc; candFeat[rank] = f; candLabel[rank] = c;
      candBox[rank][0] = boxes[gg * 4 + 0] + off;
      candBox[rank][1] = boxes[gg * 4 + 1] + off;
      candBox[rank][2] = boxes[gg * 4 + 2] + off;
      candBox[rank][3] = boxes[gg * 4 + 3] + off;
    }
  }
  __syncthreads();

  // (e) pairwise IoU, folded triangular indexing: 19900 pairs (j < i)
  for (int p = tid; p < (NCAND * (NCAND - 1)) / 2; p += 1024) {
    int r = p / (NCAND / 2), cc = p - r * (NCAND / 2);
    int i, j;
    if (cc <= r) { i = r + 1; j = cc; }
    else         { i = NCAND - 1 - r; j = NCAND - 1 - cc; }
    float ax1 = candBox[i][0], ay1 = candBox[i][1], ax2 = candBox[i][2], ay2 = candBox[i][3];
    float bx1 = candBox[j][0], by1 = candBox[j][1], bx2 = candBox[j][2], by2 = candBox[j][3];
    float areaA = (ax2 - ax1) * (ay2 - ay1);
    float areaB = (bx2 - bx1) * (by2 - by1);
    float lx = fmaxf(ax1, bx1), ly = fmaxf(ay1, by1);
    float rx = fminf(ax2, bx2), ry = fminf(ay2, by2);
    float w = fmaxf(rx - lx, 0.0f), h = fmaxf(ry - ly, 0.0f);
    float inter = w * h;
    float iou = inter / ((areaA + areaB - inter) + 1e-9f);
    if (iou > NMS_THR) atomicOr(&supp[i][j >> 6], 1ull << (j & 63));
  }
  __syncthreads();

  // (f) PARALLEL greedy NMS via Jacobi fixpoint (converges to serial-greedy)
  bool valid_i = (tid < NCAND) ? (candScore[tid] > -0.5f) : false;
  {
    u64 b = __ballot(valid_i);
    if ((tid & 63) == 0 && (tid >> 6) < 4) keepW[tid >> 6] = b;
  }
  __syncthreads();
  for (int it = 0; it < NCAND; ++it) {
    if (tid == 0) sChanged = 0;
    __syncthreads();
    bool newk = false;
    if (tid < NCAND) {
      bool sup = ((supp[tid][0] & keepW[0]) | (supp[tid][1] & keepW[1]) |
                  (supp[tid][2] & keepW[2]) | (supp[tid][3] & keepW[3])) != 0ull;
      newk = valid_i && !sup;
    }
    u64 b = __ballot(newk);
    __syncthreads();                 // everyone done reading old keepW
    if ((tid & 63) == 0 && (tid >> 6) < 4) {
      if (b != keepW[tid >> 6]) { keepW[tid >> 6] = b; atomicOr(&sChanged, 1); }
    }
    __syncthreads();
    if (!sChanged) break;
  }

  // (g) parallel top-50 gather: kept in keep-order, then non-kept ascending
  {
    int keptN = __popcll(keepW[0]) + __popcll(keepW[1]) +
                __popcll(keepW[2]) + __popcll(keepW[3]);
    if (tid == 0) finCnt = keptN < MAX_SEGS ? keptN : MAX_SEGS;
    if (tid < NCAND) {
      int w = tid >> 6, b = tid & 63;
      u64 below = (b == 0) ? 0ull : (keepW[w] & (~0ull >> (64 - b)));
      int rank = __popcll(below);
      for (int ww = 0; ww < w; ++ww) rank += __popcll(keepW[ww]);
      bool kept = (keepW[w] >> b) & 1ull;
      if (kept) {
        if (rank < MAX_SEGS) finIdx[rank] = tid;
      } else if (keptN < MAX_SEGS) {
        int pos = keptN + (tid - rank);   // tid - rank = #non-kept below tid
        if (pos < MAX_SEGS) finIdx[pos] = tid;
      }
    }
  }
  __syncthreads();

  if (tid < MAX_SEGS) {
    int keptN = finCnt;
    int i = finIdx[tid];
    bool v = tid < keptN;
    int o = img * MAX_SEGS + tid;
    out[o] = (float)candLabel[i];
    out[scoresOff + (size_t)o] = v ? candScore[i] : 0.0f;
    out[validOff + (size_t)o] = v ? 1.0f : 0.0f;
    finFeatWs[o] = candFeat[i];
    finValidWs[o] = v ? 1 : 0;
  }
}

// ---------------- K3: bilinear 128->512 upsample + threshold ----------------
__global__ void __launch_bounds__(256)
interp_kernel(const float* __restrict__ seg, const int* __restrict__ finFeat,
              const int* __restrict__ finValid, float* __restrict__ outMasks, int F) {
  int bm = blockIdx.x;          // img*MAX_SEGS + m
  int g8 = blockIdx.y;          // src quads 8g8..8g8+7 -> out rows 32g8..32g8+31
  int tid = threadIdx.x;
  int q = tid & 127;            // col group -> cols 4q..4q+3
  int sub = tid >> 7;           // 0..1

  float* omask = outMasks + (size_t)bm * (OH * OW);

  if (!finValid[bm]) {
    v4f z = {0.0f, 0.0f, 0.0f, 0.0f};
#pragma unroll
    for (int k = 0; k < 4; ++k) {
      int Q = 8 * g8 + sub + 2 * k;
      float* ob = omask + (size_t)(4 * Q) * OW;
#pragma unroll
      for (int r = 0; r < 4; ++r)
        *(reinterpret_cast<v4f*>(ob + r * OW) + q) = z;
    }
    return;
  }
  int img = bm / MAX_SEGS;
  int f = finFeat[bm];
  const float* src = seg + ((size_t)(img * F + f)) * (FH * FW);

  __shared__ float lds[10][FW];
  {
    const v4f* s4 = reinterpret_cast<const v4f*>(src);
    for (int i = tid; i < 10 * 32; i += 256) {
      int lr = i >> 5;
      int c4 = i & 31;
      int srow = 8 * g8 - 1 + lr;
      srow = srow < 0 ? 0 : (srow > FH - 1 ? FH - 1 : srow);
      *reinterpret_cast<v4f*>(&lds[lr][c4 * 4]) = s4[srow * 32 + c4];
    }
  }
  __syncthreads();

  int qm = (q > 0) ? q - 1 : 0;
  int qp = (q < FW - 1) ? q + 1 : FW - 1;

#pragma unroll
  for (int k = 0; k < 4; ++k) {
    int Q = 8 * g8 + sub + 2 * k;
    int lr = Q - 8 * g8;
    const float* prm = lds[lr];
    const float* pr0 = lds[lr + 1];
    const float* prp = lds[lr + 2];
    float* obase = omask + (size_t)(4 * Q) * OW;

    double am = prm[qm], a0 = pr0[qm], ap = prp[qm];
    double bmv = prm[q], b0 = pr0[q], bp = prp[q];
    double cm = prm[qp], c0 = pr0[qp], cp = prp[qp];

    double A[4], Bv[4], C[4];
    if (Q == 0) {
      A[0] = a0; Bv[0] = b0; C[0] = c0;
      A[1] = a0; Bv[1] = b0; C[1] = c0;
    } else {
      A[0] = 0.375 * am + 0.625 * a0;  Bv[0] = 0.375 * bmv + 0.625 * b0;  C[0] = 0.375 * cm + 0.625 * c0;
      A[1] = 0.125 * am + 0.875 * a0;  Bv[1] = 0.125 * bmv + 0.875 * b0;  C[1] = 0.125 * cm + 0.875 * c0;
    }
    if (Q == 127) {
      A[2] = a0; Bv[2] = b0; C[2] = c0;
      A[3] = a0; Bv[3] = b0; C[3] = c0;
    } else {
      A[2] = 0.875 * a0 + 0.125 * ap;  Bv[2] = 0.875 * b0 + 0.125 * bp;  C[2] = 0.875 * c0 + 0.125 * cp;
      A[3] = 0.625 * a0 + 0.375 * ap;  Bv[3] = 0.625 * b0 + 0.375 * bp;  C[3] = 0.625 * c0 + 0.375 * cp;
    }

#pragma unroll
    for (int r = 0; r < 4; ++r) {
      double px0 = (q == 0)      ? Bv[r] : (0.375 * A[r] + 0.625 * Bv[r]);
      double px1 = (q == 0)      ? Bv[r] : (0.125 * A[r] + 0.875 * Bv[r]);
      double px2 = (q == FW - 1) ? Bv[r] : (0.875 * Bv[r] + 0.125 * C[r]);
      double px3 = (q == FW - 1) ? Bv[r] : (0.625 * Bv[r] + 0.375 * C[r]);
      v4f res;
      res.x = (px0 > 0.0) ? 1.0f : 0.0f;
      res.y = (px1 > 0.0) ? 1.0f : 0.0f;
      res.z = (px2 > 0.0) ? 1.0f : 0.0f;
      res.w = (px3 > 0.0) ? 1.0f : 0.0f;
      *(reinterpret_cast<v4f*>(obase + r * OW) + q) = res;
    }
  }
}

// ---------------- host launch ----------------
extern "C" void kernel_launch(void* const* d_in, const int* in_sizes, int n_in,
                              void* d_out, int out_size, void* d_ws, size_t ws_size,
                              hipStream_t stream) {
  const float* cls = (const float*)d_in[0];
  const float* seg = (const float*)d_in[1];
  const int B = 2;  // fixed by setup_inputs
  int totalF = in_sizes[0] / NCLS1;      // 200
  int F = totalF / B;                    // 100

  float* out = (float*)d_out;
  u64*   keysWs  = (u64*)d_ws;                              // B*8000 u64
  float* boxes   = (float*)(keysWs + (size_t)B * F * NUM_CLASSES);
  int*   finFeat = (int*)(boxes + (size_t)totalF * 4);
  int*   finValid = finFeat + B * MAX_SEGS;

  const size_t labelsN   = (size_t)B * MAX_SEGS;             // 100
  const size_t maskElems = (size_t)B * MAX_SEGS * OH * OW;   // 26,214,400
  const size_t scoresOff = labelsN + maskElems;
  const size_t validOff  = scoresOff + labelsN;

  boxkey_kernel<<<totalF, 256, 0, stream>>>(cls, seg, F, boxes, keysWs);
  select_kernel<<<B, 1024, 0, stream>>>(keysWs, boxes, F, out,
                                        finFeat, finValid, scoresOff, validOff);
  interp_kernel<<<dim3(B * MAX_SEGS, 16), 256, 0, stream>>>(seg, finFeat, finValid,
                                                            out + labelsN, F);
}